// Round 3
// baseline (2699.853 us; speedup 1.0000x reference)
//
#include <hip/hip_runtime.h>
#include <hip/hip_bf16.h>
#include <stdint.h>

#define TT 256

typedef __attribute__((ext_vector_type(4))) float f32x4;
typedef __attribute__((ext_vector_type(8))) short s16x8;

#define DEV static __device__ __forceinline__

DEV short f2bf(float f){
  union{float f; uint32_t u;} v; v.f = f;
  uint32_t r = v.u + 0x7fffu + ((v.u>>16)&1u);
  return (short)(r>>16);
}
DEV float bf2f(uint32_t u16){
  union{uint32_t u; float f;} v; v.u = u16<<16; return v.f;
}
DEV uint32_t pk2(float a, float b){
  return (uint32_t)(uint16_t)f2bf(a) | ((uint32_t)(uint16_t)f2bf(b)<<16);
}
DEV float sigm(float x){ return 1.f/(1.f + __expf(-x)); }
DEV float tanh_f(float x){ float e = __expf(2.f*x); return 1.f - 2.f/(e+1.f); }
DEV f32x4 MFMA(s16x8 a, s16x8 b, f32x4 c){
  return __builtin_amdgcn_mfma_f32_16x16x32_bf16(a, b, c, 0, 0, 0);
}

// ---------------- Wih1 -> B-fragment layout (bf16) ----------------
// Wih1f[dir][ntg(32)][kt(8)][lane(64)][8];  n = ntg*16 + (lane&15), k = (lane>>4)*8+j
__global__ __launch_bounds__(256) void prep_wih1(
    const float* __restrict__ Wih1, uint16_t* __restrict__ Wih1f)
{
  int tid = blockIdx.x*256 + threadIdx.x;   // 32768 total
  int l = tid & 63, kt = (tid>>6)&7, ntg = (tid>>9)&31, dir = (tid>>14)&1;
  int lm = l&15, lk = l>>4;
  int n = ntg*16 + lm;
  const float* p = Wih1 + ((size_t)(dir*512 + n))*256 + kt*32 + lk*8;
  s16x8 o;
  #pragma unroll
  for (int j=0; j<8; ++j) o[j] = f2bf(p[j]);
  *(s16x8*)(Wih1f + (size_t)tid*8) = o;
}

// ---------------- BiLSTM layer 0 (LN fused; D_IN=6 -> H=128/dir) ----------------
template<int NS>
__global__ __launch_bounds__(512,2) void lstm0_kernel(
    const float* __restrict__ x, const float* __restrict__ lng,
    const float* __restrict__ lnb,
    const float* __restrict__ Wih0, const float* __restrict__ Whh0,
    const float* __restrict__ bih0, const float* __restrict__ bhh0,
    uint16_t* __restrict__ h0, int nb, int BR, int b_off)
{
  const int dir = blockIdx.x / nb, bg = blockIdx.x % nb;
  const int tid = threadIdx.x, w = tid>>6, l = tid&63;
  const int lm = l&15, lk = l>>4;
  const int gb = b_off + bg*NS;

  __shared__ short hbuf[2][2048];        // double-buffered h, XOR(row<<4) swizzle
  __shared__ short xnbf[TT*NS*8];        // [t][r][8] bf16 (K=6 padded to 8)

  for (int i=tid; i<4096; i+=512) ((short*)hbuf)[i] = 0;

  // LN fused staging
  for (int pr=tid; pr<TT*NS; pr+=512){
    int r = pr >> 8, t = pr & 255;
    const float* px = x + ((size_t)(gb+r)*TT + t)*6;
    float v[6]; float mu=0.f, var=0.f;
    #pragma unroll
    for (int d=0; d<6; ++d){ v[d]=px[d]; mu+=v[d]; }
    mu *= (1.f/6.f);
    #pragma unroll
    for (int d=0; d<6; ++d){ float dd=v[d]-mu; var+=dd*dd; }
    float rs = rsqrtf(var*(1.f/6.f) + 1e-5f);
    s16x8 vv;
    #pragma unroll
    for (int d=0; d<6; ++d) vv[d] = f2bf((v[d]-mu)*rs*lng[d] + lnb[d]);
    vv[6]=0; vv[7]=0;
    *(s16x8*)&xnbf[(t*NS + r)*8] = vv;
  }

  // wave w owns gate cols c = w*16 + lm, gates G=0..3 at n = G*128 + c
  const int c = w*16 + lm;
  s16x8 bw[4][4], bx[4];
  float biasc[4];
  #pragma unroll
  for (int G=0; G<4; ++G){
    const int n = G*128 + c;
    biasc[G] = bih0[dir*512+n] + bhh0[dir*512+n];
    #pragma unroll
    for (int kt=0; kt<4; ++kt){
      const float* p = Whh0 + ((size_t)(dir*512+n)*128 + kt*32 + lk*8);
      s16x8 tmp;
      #pragma unroll
      for (int j=0; j<8; ++j) tmp[j] = f2bf(p[j]);
      bw[G][kt] = tmp;
    }
    s16x8 tx;
    #pragma unroll
    for (int j=0; j<8; ++j){
      int k = lk*8 + j;
      tx[j] = (k<6) ? f2bf(Wih0[(size_t)(dir*512+(G*128+c))*6 + k]) : (short)0;
    }
    bx[G] = tx;
  }

  const int r0 = ((l>>4)&1)*4 + ((l<32)?0:2);
  float cst[2] = {0.f, 0.f};
  __syncthreads();

  for (int t=0; t<TT; ++t){
    const int tt = dir ? (TT-1-t) : t;
    const int rd = t & 1;
    s16x8 ah[4];
    #pragma unroll
    for (int kt=0; kt<4; ++kt){
      int off = rd*4096 + lm*256 + ((kt*64 + lk*16) ^ (lm<<4));
      ah[kt] = *(const s16x8*)((const char*)hbuf + off);
    }
    s16x8 ax = {0,0,0,0,0,0,0,0};
    if (l < NS) ax = *(const s16x8*)&xnbf[(tt*NS + l)*8];

    f32x4 acc[4];
    #pragma unroll
    for (int G=0; G<4; ++G){
      f32x4 a = {0.f,0.f,0.f,0.f};
      #pragma unroll
      for (int kt=0; kt<4; ++kt) a = MFMA(ah[kt], bw[G][kt], a);
      a = MFMA(ax, bx[G], a);
      acc[G] = a;
    }

    float g0[4], g1[4];
    #pragma unroll
    for (int G=0; G<4; ++G){
      float o2 = __shfl(acc[G][2], l & 31);
      float o3 = __shfl(acc[G][3], l & 31);
      g0[G] = ((l<32) ? acc[G][0] : o2) + biasc[G];
      g1[G] = ((l<32) ? acc[G][1] : o3) + biasc[G];
    }
    float hv[2];
    {
      float cc = sigm(g0[1])*cst[0] + sigm(g0[0])*tanh_f(g0[2]);
      cst[0] = cc; hv[0] = sigm(g0[3])*tanh_f(cc);
      cc = sigm(g1[1])*cst[1] + sigm(g1[0])*tanh_f(g1[2]);
      cst[1] = cc; hv[1] = sigm(g1[3])*tanh_f(cc);
    }

    if (r0 < NS){
      #pragma unroll
      for (int q=0; q<2; ++q){
        int r = r0 + q;
        short hb = f2bf(hv[q]);
        *(short*)((char*)hbuf + ((rd^1)*4096 + r*256 + ((c*2) ^ (r<<4)))) = hb;
        h0[((size_t)tt*BR + bg*NS + r)*256 + dir*128 + c] = (uint16_t)hb;
      }
    }
    __syncthreads();
  }
}

// ---------------- BiLSTM layer 1 (256 -> 128/dir), fused xp ----------------
template<int NS>
__global__ __launch_bounds__(512,2) void lstm1_kernel(
    const uint16_t* __restrict__ h0, const uint16_t* __restrict__ Wih1f,
    const float* __restrict__ Whh1, const float* __restrict__ bih1,
    const float* __restrict__ bhh1, uint16_t* __restrict__ h1,
    int nb, int BR)
{
  constexpr int MT = NS/2;               // m-tiles per 8-step chunk
  const int dir = blockIdx.x / nb, bg = blockIdx.x % nb;
  const int tid = threadIdx.x, w = tid>>6, l = tid&63;
  const int lm = l&15, lk = l>>4;

  __shared__ short hbuf[2][2048];
  __shared__ short abuf[8*NS*256];       // chunk of h0: [8*NS rows][256], swizzled

  for (int i=tid; i<4096; i+=512) ((short*)hbuf)[i] = 0;

  const int c = w*16 + lm;
  s16x8 bw[4][4];
  float biasv[4];
  #pragma unroll
  for (int G=0; G<4; ++G){
    const int n = G*128 + c;
    biasv[G] = bih1[dir*512+n] + bhh1[dir*512+n];
    #pragma unroll
    for (int kt=0; kt<4; ++kt){
      const float* p = Whh1 + ((size_t)(dir*512+n)*128 + kt*32 + lk*8);
      s16x8 tmp;
      #pragma unroll
      for (int j=0; j<8; ++j) tmp[j] = f2bf(p[j]);
      bw[G][kt] = tmp;
    }
  }

  const int r0 = ((l>>4)&1)*4 + ((l<32)?0:2);
  float cst[2] = {0.f,0.f};
  uint32_t xpk[4][MT][2];
  __syncthreads();

  for (int ch=0; ch<32; ++ch){
    // ---- stage chunk rows m = s*NS + b ----
    for (int sid=tid; sid<8*NS*32; sid+=512){
      int row = sid >> 5, sl = sid & 31;
      int s = row / NS, b = row & (NS-1);
      int tg = dir ? (TT-1-(ch*8+s)) : (ch*8+s);
      s16x8 v = *(const s16x8*)(h0 + ((size_t)tg*BR + bg*NS + b)*256 + sl*8);
      *(s16x8*)((char*)abuf + row*512 + ((sl ^ (row&15))<<4)) = v;
    }
    __syncthreads();

    // ---- phase A: xp for the chunk (G-outer, bfr hoisted over m-tiles) ----
    #pragma unroll
    for (int G=0; G<4; ++G){
      f32x4 acc[MT];
      #pragma unroll
      for (int mt=0; mt<MT; ++mt) acc[mt] = (f32x4){biasv[G],biasv[G],biasv[G],biasv[G]};
      #pragma unroll
      for (int kt=0; kt<8; ++kt){
        s16x8 bfr = *(const s16x8*)(Wih1f + (((size_t)(dir*32 + G*8 + w)*8 + kt)*64 + l)*8);
        #pragma unroll
        for (int mt=0; mt<MT; ++mt){
          int row = mt*16 + lm;
          s16x8 afr = *(const s16x8*)((const char*)abuf + row*512 + (((kt*4+lk) ^ (row&15))<<4));
          acc[mt] = MFMA(afr, bfr, acc[mt]);
        }
      }
      #pragma unroll
      for (int mt=0; mt<MT; ++mt){
        xpk[G][mt][0] = pk2(acc[mt][0], acc[mt][1]);
        xpk[G][mt][1] = pk2(acc[mt][2], acc[mt][3]);
      }
    }

    // ---- phase B: 8 recurrent steps ----
    #pragma unroll
    for (int s=0; s<8; ++s){
      const int gs = ch*8 + s;
      const int rd = gs & 1;
      const int tg = dir ? (TT-1-gs) : gs;

      // gather xp into C-fragment layout (rows lk*4+j)
      f32x4 acc4[4];
      #pragma unroll
      for (int G=0; G<4; ++G){
        #pragma unroll
        for (int p=0; p<2; ++p){
          const int base = s*NS + 2*p;           // static
          const int mt_s = (base>>4) < MT ? (base>>4) : MT-1;
          const int word = (base & 3) >> 1;       // static
          int q = (base + lk*4) >> 2;
          int src = (q & 3)*16 + lm;
          uint32_t pw = (uint32_t)__shfl((int)xpk[G][mt_s][word], src);
          acc4[G][2*p  ] = bf2f(pw & 0xffffu);
          acc4[G][2*p+1] = bf2f(pw >> 16);
        }
      }

      s16x8 ah[4];
      #pragma unroll
      for (int kt=0; kt<4; ++kt){
        int off = rd*4096 + lm*256 + ((kt*64 + lk*16) ^ (lm<<4));
        ah[kt] = *(const s16x8*)((const char*)hbuf + off);
      }
      #pragma unroll
      for (int G=0; G<4; ++G){
        #pragma unroll
        for (int kt=0; kt<4; ++kt)
          acc4[G] = MFMA(ah[kt], bw[G][kt], acc4[G]);
      }

      float g0[4], g1[4];
      #pragma unroll
      for (int G=0; G<4; ++G){
        float o2 = __shfl(acc4[G][2], l & 31);
        float o3 = __shfl(acc4[G][3], l & 31);
        g0[G] = (l<32) ? acc4[G][0] : o2;
        g1[G] = (l<32) ? acc4[G][1] : o3;
      }
      float hv[2];
      float cc = sigm(g0[1])*cst[0] + sigm(g0[0])*tanh_f(g0[2]);
      cst[0] = cc; hv[0] = sigm(g0[3])*tanh_f(cc);
      cc = sigm(g1[1])*cst[1] + sigm(g1[0])*tanh_f(g1[2]);
      cst[1] = cc; hv[1] = sigm(g1[3])*tanh_f(cc);

      if (r0 < NS){
        #pragma unroll
        for (int q2=0; q2<2; ++q2){
          int r = r0 + q2;
          short hb = f2bf(hv[q2]);
          *(short*)((char*)hbuf + ((rd^1)*4096 + r*256 + ((c*2) ^ (r<<4)))) = hb;
          h1[((size_t)tg*BR + bg*NS + r)*256 + dir*128 + c] = (uint16_t)hb;
        }
      }
      __syncthreads();
    }
  }
}

// ---------------- attention scores ----------------
__global__ __launch_bounds__(256,2) void scores_kernel(
    const uint16_t* __restrict__ h1, const float* __restrict__ Wa1,
    const float* __restrict__ ba1, const float* __restrict__ Wa2,
    const float* __restrict__ ba2, float* __restrict__ scores,
    int nbb, int BR)
{
  const int bx = blockIdx.x;
  const int t = bx / nbb, bb = (bx - t*nbb) * 64;
  const int tid = threadIdx.x, w = tid>>6, l = tid&63;
  const int lm = l&15, lk = l>>4;
  __shared__ short abuf[64*256];
  __shared__ float scred[4][64];

  #pragma unroll
  for (int it=0; it<8; ++it){
    int sid = it*256 + tid, row = sid>>5, sl = sid&31;
    s16x8 v = *(const s16x8*)(h1 + ((size_t)t*BR + bb + row)*256 + sl*8);
    *(s16x8*)((char*)abuf + row*512 + ((sl ^ (row&15))<<4)) = v;
  }

  s16x8 bwa[2][8]; float b1v[2], wa2v[2];
  #pragma unroll
  for (int nt=0; nt<2; ++nt){
    int n = w*32 + nt*16 + lm;
    b1v[nt] = ba1[n]; wa2v[nt] = Wa2[n];
    #pragma unroll
    for (int kt=0; kt<8; ++kt){
      const float* p = Wa1 + (size_t)n*256 + kt*32 + lk*8;
      s16x8 tmp;
      #pragma unroll
      for (int j=0; j<8; ++j) tmp[j] = f2bf(p[j]);
      bwa[nt][kt] = tmp;
    }
  }
  __syncthreads();

  #pragma unroll
  for (int mt=0; mt<4; ++mt){
    f32x4 a0 = {b1v[0],b1v[0],b1v[0],b1v[0]};
    f32x4 a1 = {b1v[1],b1v[1],b1v[1],b1v[1]};
    #pragma unroll
    for (int kt=0; kt<8; ++kt){
      int row = mt*16 + lm;
      s16x8 af = *(const s16x8*)((const char*)abuf + row*512 + (((kt*4+lk) ^ (row&15))<<4));
      a0 = MFMA(af, bwa[0][kt], a0);
      a1 = MFMA(af, bwa[1][kt], a1);
    }
    #pragma unroll
    for (int j=0; j<4; ++j){
      float pj = tanh_f(a0[j])*wa2v[0] + tanh_f(a1[j])*wa2v[1];
      #pragma unroll
      for (int m=1; m<16; m<<=1) pj += __shfl_xor(pj, m);
      if (lm == 0) scred[w][mt*16 + lk*4 + j] = pj;
    }
  }
  __syncthreads();
  if (tid < 64){
    float s = scred[0][tid]+scred[1][tid]+scred[2][tid]+scred[3][tid] + ba2[0];
    scores[(size_t)(bb+tid)*TT + t] = s;
  }
}

// ---------------- softmax over T + context ----------------
__global__ __launch_bounds__(256,2) void ctx_kernel(
    const uint16_t* __restrict__ h1, const float* __restrict__ scores,
    float* __restrict__ context, int BR)
{
  const int b = blockIdx.x, tid = threadIdx.x;
  __shared__ float at[TT];
  __shared__ float red[8];
  float sc = scores[(size_t)b*TT + tid];
  float m = sc;
  #pragma unroll
  for (int d=1; d<64; d<<=1) m = fmaxf(m, __shfl_xor(m, d));
  if ((tid&63)==0) red[tid>>6] = m;
  __syncthreads();
  m = fmaxf(fmaxf(red[0],red[1]), fmaxf(red[2],red[3]));
  float e = __expf(sc - m);
  float s = e;
  #pragma unroll
  for (int d=1; d<64; d<<=1) s += __shfl_xor(s, d);
  if ((tid&63)==0) red[4+(tid>>6)] = s;
  __syncthreads();
  s = red[4]+red[5]+red[6]+red[7];
  at[tid] = e / s;
  __syncthreads();

  float acc = 0.f;
  const uint16_t* hp = h1 + (size_t)b*256 + tid;
  #pragma unroll 4
  for (int t2=0; t2<TT; ++t2) acc += at[t2] * bf2f(hp[(size_t)t2*BR*256]);
  context[(size_t)b*256 + tid] = acc;
}

// ---------------- head ----------------
__global__ __launch_bounds__(128,2) void head_kernel(
    const float* __restrict__ ctx, const float* __restrict__ Wf1,
    const float* __restrict__ bf1, const float* __restrict__ g2,
    const float* __restrict__ b2, const float* __restrict__ Wf2,
    const float* __restrict__ bf2v, float* __restrict__ out, int b_off)
{
  const int b = blockIdx.x, tid = threadIdx.x;
  __shared__ float cx[256];
  __shared__ float zb[128];
  __shared__ float red[4];
  cx[tid]       = ctx[(size_t)b*256 + tid];
  cx[128+tid]   = ctx[(size_t)b*256 + 128 + tid];
  __syncthreads();
  float y = bf1[tid];
  const float* wr = Wf1 + (size_t)tid*256;
  #pragma unroll 8
  for (int k=0; k<256; ++k) y += cx[k]*wr[k];
  float s = y;
  #pragma unroll
  for (int d=1; d<64; d<<=1) s += __shfl_xor(s, d);
  if ((tid&63)==0) red[tid>>6] = s;
  __syncthreads();
  float mu = (red[0]+red[1])*(1.f/128.f);
  float dv = y - mu;
  float q = dv*dv;
  #pragma unroll
  for (int d=1; d<64; d<<=1) q += __shfl_xor(q, d);
  if ((tid&63)==0) red[2+(tid>>6)] = q;
  __syncthreads();
  float var = (red[2]+red[3])*(1.f/128.f);
  float z = dv*rsqrtf(var + 1e-5f)*g2[tid] + b2[tid];
  z = fmaxf(z, 0.f);
  zb[tid] = z;
  __syncthreads();
  if (tid < 5){
    float o = bf2v[tid];
    const float* wp = Wf2 + (size_t)tid*128;
    for (int k=0; k<128; ++k) o += zb[k]*wp[k];
    out[(size_t)(b_off + b)*5 + tid] = o;
  }
}

extern "C" void kernel_launch(void* const* d_in, const int* in_sizes, int n_in,
                              void* d_out, int out_size, void* d_ws, size_t ws_size,
                              hipStream_t stream)
{
  const float* x    = (const float*)d_in[0];
  const float* ln_g = (const float*)d_in[1];
  const float* ln_b = (const float*)d_in[2];
  const float* Wih0 = (const float*)d_in[3];
  const float* Whh0 = (const float*)d_in[4];
  const float* bih0 = (const float*)d_in[5];
  const float* bhh0 = (const float*)d_in[6];
  const float* Wih1 = (const float*)d_in[7];
  const float* Whh1 = (const float*)d_in[8];
  const float* bih1 = (const float*)d_in[9];
  const float* bhh1 = (const float*)d_in[10];
  const float* Wa1  = (const float*)d_in[11];
  const float* ba1  = (const float*)d_in[12];
  const float* Wa2  = (const float*)d_in[13];
  const float* ba2  = (const float*)d_in[14];
  const float* Wf1  = (const float*)d_in[15];
  const float* bf1  = (const float*)d_in[16];
  const float* ln2g = (const float*)d_in[17];
  const float* ln2b = (const float*)d_in[18];
  const float* Wf2  = (const float*)d_in[19];
  const float* bf2  = (const float*)d_in[20];

  auto align256 = [](size_t v) -> size_t { return (v + 255) & ~(size_t)255; };
  const size_t W1S = align256((size_t)2*32*8*64*8*2);

  // choose BR: full batch (one round) if h1+h0+W1f fit; scores/ctx alias dead h0.
  int BR = 1024;
  {
    size_t need = 2*align256((size_t)TT*1024*256*2) + W1S;
    if (need > ws_size) BR = 512;
  }
  const int NS = (BR == 1024) ? 4 : 2;
  const int nb = BR / NS;

  char* wsb = (char*)d_ws;
  const size_t Hb = align256((size_t)TT*BR*256*2);
  uint16_t* h1 = (uint16_t*)wsb;
  uint16_t* h0 = (uint16_t*)(wsb + Hb);
  uint16_t* W1f;
  float *scoresP, *ctxP;
  if (BR == 1024){
    W1f     = (uint16_t*)(wsb + 2*Hb);
    scoresP = (float*)h0;                                 // h0 dead after lstm1
    ctxP    = (float*)(wsb + Hb + align256((size_t)BR*TT*4));
  } else {
    W1f     = (uint16_t*)(wsb + 2*Hb);
    scoresP = (float*)(wsb + 2*Hb + W1S);
    ctxP    = (float*)(wsb + 2*Hb + W1S + align256((size_t)BR*TT*4));
  }

  prep_wih1 <<<128, 256, 0, stream>>>(Wih1, W1f);

  for (int b_off = 0; b_off < 1024; b_off += BR){
    if (BR == 1024){
      lstm0_kernel<4> <<<2*nb, 512, 0, stream>>>(x, ln_g, ln_b, Wih0, Whh0, bih0, bhh0,
                                                 h0, nb, BR, b_off);
      lstm1_kernel<4> <<<2*nb, 512, 0, stream>>>(h0, W1f, Whh1, bih1, bhh1, h1, nb, BR);
    } else {
      lstm0_kernel<2> <<<2*nb, 512, 0, stream>>>(x, ln_g, ln_b, Wih0, Whh0, bih0, bhh0,
                                                 h0, nb, BR, b_off);
      lstm1_kernel<2> <<<2*nb, 512, 0, stream>>>(h0, W1f, Whh1, bih1, bhh1, h1, nb, BR);
    }
    scores_kernel <<<TT*(BR/64), 256, 0, stream>>>(h1, Wa1, ba1, Wa2, ba2, scoresP, BR/64, BR);
    ctx_kernel    <<<BR, 256, 0, stream>>>(h1, scoresP, ctxP, BR);
    head_kernel   <<<BR, 128, 0, stream>>>(ctxP, Wf1, bf1, ln2g, ln2b, Wf2, bf2,
                                           (float*)d_out, b_off);
  }
}

// Round 4
// 1082.573 us; speedup vs baseline: 2.4939x; 2.4939x over previous
//
#include <hip/hip_runtime.h>
#include <hip/hip_bf16.h>
#include <stdint.h>

#define TT 256

typedef __attribute__((ext_vector_type(4))) float f32x4;
typedef __attribute__((ext_vector_type(8))) short s16x8;

#define DEV static __device__ __forceinline__

DEV short f2bf(float f){
  union{float f; uint32_t u;} v; v.f = f;
  uint32_t r = v.u + 0x7fffu + ((v.u>>16)&1u);
  return (short)(r>>16);
}
DEV float bf2f(uint32_t u16){
  union{uint32_t u; float f;} v; v.u = u16<<16; return v.f;
}
DEV uint32_t pk2(float a, float b){
  return (uint32_t)(uint16_t)f2bf(a) | ((uint32_t)(uint16_t)f2bf(b)<<16);
}
DEV float sigm(float x){ return 1.f/(1.f + __expf(-x)); }
DEV float tanh_f(float x){ float e = __expf(2.f*x); return 1.f - 2.f/(e+1.f); }
DEV f32x4 MFMA(s16x8 a, s16x8 b, f32x4 c){
  return __builtin_amdgcn_mfma_f32_16x16x32_bf16(a, b, c, 0, 0, 0);
}
DEV s16x8 cvt8(const float* p){
  f32x4 a = *(const f32x4*)p;
  f32x4 b = *(const f32x4*)(p+4);
  s16x8 o;
  o[0]=f2bf(a[0]); o[1]=f2bf(a[1]); o[2]=f2bf(a[2]); o[3]=f2bf(a[3]);
  o[4]=f2bf(b[0]); o[5]=f2bf(b[1]); o[6]=f2bf(b[2]); o[7]=f2bf(b[3]);
  return o;
}

// ================= BiLSTM layer 0 (LN fused; 6 -> 128/dir), NS=8 =================
DEV void lstm0_dev(const float* __restrict__ x, const float* __restrict__ lng,
                   const float* __restrict__ lnb,
                   const float* __restrict__ Wih0, const float* __restrict__ Whh0,
                   const float* __restrict__ bih0, const float* __restrict__ bhh0,
                   uint16_t* __restrict__ h0, int dir, int bg, int BR, int b_off,
                   short* hbuf, short* xnbf)
{
  const int tid = threadIdx.x, w = tid>>6, l = tid&63;
  const int lm = l&15, lk = l>>4;
  const int gb = b_off + bg*8;

  for (int i=tid; i<4096; i+=512) hbuf[i] = 0;

  // LN fused staging: [t][r][8] bf16 (K=6 padded)
  for (int pr=tid; pr<2048; pr+=512){
    int r = pr >> 8, t = pr & 255;
    const float* px = x + ((size_t)(gb+r)*TT + t)*6;
    float v[6]; float mu=0.f, var=0.f;
    #pragma unroll
    for (int d=0; d<6; ++d){ v[d]=px[d]; mu+=v[d]; }
    mu *= (1.f/6.f);
    #pragma unroll
    for (int d=0; d<6; ++d){ float dd=v[d]-mu; var+=dd*dd; }
    float rs = rsqrtf(var*(1.f/6.f) + 1e-5f);
    s16x8 vv;
    #pragma unroll
    for (int d=0; d<6; ++d) vv[d] = f2bf((v[d]-mu)*rs*lng[d] + lnb[d]);
    vv[6]=0; vv[7]=0;
    *(s16x8*)&xnbf[(t*8 + r)*8] = vv;
  }

  const int c = w*16 + lm;
  s16x8 bw[4][4], bx[4];
  float biasc[4];
  #pragma unroll
  for (int G=0; G<4; ++G){
    const int n = G*128 + c;
    biasc[G] = bih0[dir*512+n] + bhh0[dir*512+n];
    #pragma unroll
    for (int kt=0; kt<4; ++kt)
      bw[G][kt] = cvt8(Whh0 + ((size_t)(dir*512+n))*128 + kt*32 + lk*8);
    s16x8 tx;
    #pragma unroll
    for (int j=0; j<8; ++j){
      int k = lk*8 + j;
      tx[j] = (k<6) ? f2bf(Wih0[(size_t)(dir*512+n)*6 + k]) : (short)0;
    }
    bx[G] = tx;
  }

  const int r0 = ((l>>4)&1)*4 + ((l<32)?0:2);
  float cst[2] = {0.f, 0.f};
  __syncthreads();

  for (int t=0; t<TT; ++t){
    const int tt = dir ? (TT-1-t) : t;
    const int rd = t & 1;
    s16x8 ah[4];
    #pragma unroll
    for (int kt=0; kt<4; ++kt){
      int off = rd*4096 + lm*256 + ((kt*64 + lk*16) ^ (lm<<4));
      ah[kt] = *(const s16x8*)((const char*)hbuf + off);
    }
    s16x8 ax = {0,0,0,0,0,0,0,0};
    if (l < 8) ax = *(const s16x8*)&xnbf[(tt*8 + l)*8];

    f32x4 acc[4];
    #pragma unroll
    for (int G=0; G<4; ++G){
      f32x4 a = {0.f,0.f,0.f,0.f};
      #pragma unroll
      for (int kt=0; kt<4; ++kt) a = MFMA(ah[kt], bw[G][kt], a);
      a = MFMA(ax, bx[G], a);
      acc[G] = a;
    }

    float g0[4], g1[4];
    #pragma unroll
    for (int G=0; G<4; ++G){
      float o2 = __shfl(acc[G][2], l & 31);
      float o3 = __shfl(acc[G][3], l & 31);
      g0[G] = ((l<32) ? acc[G][0] : o2) + biasc[G];
      g1[G] = ((l<32) ? acc[G][1] : o3) + biasc[G];
    }
    float hv[2];
    {
      float cc = sigm(g0[1])*cst[0] + sigm(g0[0])*tanh_f(g0[2]);
      cst[0] = cc; hv[0] = sigm(g0[3])*tanh_f(cc);
      cc = sigm(g1[1])*cst[1] + sigm(g1[0])*tanh_f(g1[2]);
      cst[1] = cc; hv[1] = sigm(g1[3])*tanh_f(cc);
    }

    #pragma unroll
    for (int q=0; q<2; ++q){
      int r = r0 + q;
      short hb = f2bf(hv[q]);
      *(short*)((char*)hbuf + ((rd^1)*4096 + r*256 + ((c*2) ^ (r<<4)))) = hb;
      h0[((size_t)tt*BR + bg*8 + r)*256 + dir*128 + c] = (uint16_t)hb;
    }
    __syncthreads();
  }
}

// ============ BiLSTM layer 1 (256 -> 128/dir), fused xp, NS=8, T14 staging ============
DEV void lstm1_dev(const uint16_t* __restrict__ h0, const float* __restrict__ Wih1,
                   const float* __restrict__ Whh1, const float* __restrict__ bih1,
                   const float* __restrict__ bhh1, uint16_t* __restrict__ h1,
                   int dir, int bg, int BR, short* hbuf, short* abuf)
{
  const int tid = threadIdx.x, w = tid>>6, l = tid&63;
  const int lm = l&15, lk = l>>4;

  for (int i=tid; i<4096; i+=512) hbuf[i] = 0;

  const int c = w*16 + lm;
  s16x8 bw[4][4];
  float biasv[4];
  #pragma unroll
  for (int G=0; G<4; ++G){
    const int n = G*128 + c;
    biasv[G] = bih1[dir*512+n] + bhh1[dir*512+n];
    #pragma unroll
    for (int kt=0; kt<4; ++kt)
      bw[G][kt] = cvt8(Whh1 + ((size_t)(dir*512+n))*128 + kt*32 + lk*8);
  }

  const int r0 = ((l>>4)&1)*4 + ((l<32)?0:2);
  float cst[2] = {0.f,0.f};
  uint32_t xpk[4][4][2];
  s16x8 vst[4];

  // prologue: load chunk 0 to regs
  #pragma unroll
  for (int it=0; it<4; ++it){
    int sid = it*512 + tid, row = sid>>5, sl = sid&31, s = row>>3, b = row&7;
    int tg = dir ? (TT-1-s) : s;
    vst[it] = *(const s16x8*)(h0 + ((size_t)tg*BR + bg*8 + b)*256 + sl*8);
  }
  __syncthreads();

  for (int ch=0; ch<32; ++ch){
    const int cur = ch & 1;
    // write staged regs -> abuf[cur] (swizzled)
    #pragma unroll
    for (int it=0; it<4; ++it){
      int sid = it*512 + tid, row = sid>>5, sl = sid&31;
      *(s16x8*)((char*)abuf + cur*32768 + row*512 + ((sl ^ (row&15))<<4)) = vst[it];
    }
    __syncthreads();

    // phase A: xp for 8 steps; W-fragments straight from fp32 Wih1 (L2-resident)
    #pragma unroll
    for (int G=0; G<4; ++G){
      f32x4 acc[4];
      #pragma unroll
      for (int mt=0; mt<4; ++mt) acc[mt] = (f32x4){biasv[G],biasv[G],biasv[G],biasv[G]};
      #pragma unroll
      for (int kt=0; kt<8; ++kt){
        s16x8 bfr = cvt8(Wih1 + ((size_t)(dir*512 + G*128 + c))*256 + kt*32 + lk*8);
        #pragma unroll
        for (int mt=0; mt<4; ++mt){
          int row = mt*16 + lm;
          s16x8 afr = *(const s16x8*)((const char*)abuf + cur*32768 + row*512
                                      + (((kt*4+lk) ^ (row&15))<<4));
          acc[mt] = MFMA(afr, bfr, acc[mt]);
        }
      }
      #pragma unroll
      for (int mt=0; mt<4; ++mt){
        xpk[G][mt][0] = pk2(acc[mt][0], acc[mt][1]);
        xpk[G][mt][1] = pk2(acc[mt][2], acc[mt][3]);
      }
    }

    // issue next chunk's global loads early (latency hides under phase B)
    if (ch < 31){
      #pragma unroll
      for (int it=0; it<4; ++it){
        int sid = it*512 + tid, row = sid>>5, sl = sid&31, s = row>>3, b = row&7;
        int tg = dir ? (TT-1-((ch+1)*8+s)) : ((ch+1)*8+s);
        vst[it] = *(const s16x8*)(h0 + ((size_t)tg*BR + bg*8 + b)*256 + sl*8);
      }
    }

    // phase B: 8 recurrent steps
    #pragma unroll
    for (int s=0; s<8; ++s){
      const int gs = ch*8 + s;
      const int rd = gs & 1;
      const int tg = dir ? (TT-1-gs) : gs;
      const int mt = s>>1;

      f32x4 acc4[4];
      #pragma unroll
      for (int G=0; G<4; ++G){
        uint32_t p0 = xpk[G][mt][0], p1 = xpk[G][mt][1];
        if (s & 1){
          p0 = (uint32_t)__shfl((int)p0, (l+32)&63);
          p1 = (uint32_t)__shfl((int)p1, (l+32)&63);
        }
        acc4[G] = (f32x4){bf2f(p0&0xffffu), bf2f(p0>>16), bf2f(p1&0xffffu), bf2f(p1>>16)};
      }

      s16x8 ah[4];
      #pragma unroll
      for (int kt=0; kt<4; ++kt){
        int off = rd*4096 + lm*256 + ((kt*64 + lk*16) ^ (lm<<4));
        ah[kt] = *(const s16x8*)((const char*)hbuf + off);
      }
      #pragma unroll
      for (int G=0; G<4; ++G){
        #pragma unroll
        for (int kt=0; kt<4; ++kt)
          acc4[G] = MFMA(ah[kt], bw[G][kt], acc4[G]);
      }

      float g0[4], g1[4];
      #pragma unroll
      for (int G=0; G<4; ++G){
        float o2 = __shfl(acc4[G][2], l & 31);
        float o3 = __shfl(acc4[G][3], l & 31);
        g0[G] = (l<32) ? acc4[G][0] : o2;
        g1[G] = (l<32) ? acc4[G][1] : o3;
      }
      float hv[2];
      float cc = sigm(g0[1])*cst[0] + sigm(g0[0])*tanh_f(g0[2]);
      cst[0] = cc; hv[0] = sigm(g0[3])*tanh_f(cc);
      cc = sigm(g1[1])*cst[1] + sigm(g1[0])*tanh_f(g1[2]);
      cst[1] = cc; hv[1] = sigm(g1[3])*tanh_f(cc);

      #pragma unroll
      for (int q=0; q<2; ++q){
        int r = r0 + q;
        short hb = f2bf(hv[q]);
        *(short*)((char*)hbuf + ((rd^1)*4096 + r*256 + ((c*2) ^ (r<<4)))) = hb;
        h1[((size_t)tg*BR + bg*8 + r)*256 + dir*128 + c] = (uint16_t)hb;
      }
      __syncthreads();
    }
  }
}

// ================= combined kernel: blocks [0,n0)=lstm0, rest=lstm1 =================
__global__ __launch_bounds__(512,2) void lstm_combo(
    int n0, int nb0, int BR0, int b_off0,
    const float* __restrict__ x, const float* __restrict__ lng,
    const float* __restrict__ lnb,
    const float* __restrict__ Wih0, const float* __restrict__ Whh0,
    const float* __restrict__ bih0, const float* __restrict__ bhh0,
    uint16_t* __restrict__ h0out,
    int nb1, int BR1,
    const uint16_t* __restrict__ h0in, const float* __restrict__ Wih1,
    const float* __restrict__ Whh1, const float* __restrict__ bih1,
    const float* __restrict__ bhh1, uint16_t* __restrict__ h1out)
{
  __shared__ short smem[36864];   // 72 KB: hbuf(4096) + abuf(32768)
  if ((int)blockIdx.x < n0){
    int bid = blockIdx.x;
    lstm0_dev(x, lng, lnb, Wih0, Whh0, bih0, bhh0, h0out,
              bid/nb0, bid%nb0, BR0, b_off0, smem, smem+4096);
  } else {
    int bid = blockIdx.x - n0;
    lstm1_dev(h0in, Wih1, Whh1, bih1, bhh1, h1out,
              bid/nb1, bid%nb1, BR1, smem, smem+4096);
  }
}

// ================= attention scores =================
__global__ __launch_bounds__(256,2) void scores_kernel(
    const uint16_t* __restrict__ h1, const float* __restrict__ Wa1,
    const float* __restrict__ ba1, const float* __restrict__ Wa2,
    const float* __restrict__ ba2, float* __restrict__ scores,
    int nbb, int BR)
{
  const int bx = blockIdx.x;
  const int t = bx / nbb, bb = (bx - t*nbb) * 64;
  const int tid = threadIdx.x, w = tid>>6, l = tid&63;
  const int lm = l&15, lk = l>>4;
  __shared__ short abuf[64*256];
  __shared__ float scred[4][64];

  #pragma unroll
  for (int it=0; it<8; ++it){
    int sid = it*256 + tid, row = sid>>5, sl = sid&31;
    s16x8 v = *(const s16x8*)(h1 + ((size_t)t*BR + bb + row)*256 + sl*8);
    *(s16x8*)((char*)abuf + row*512 + ((sl ^ (row&15))<<4)) = v;
  }

  s16x8 bwa[2][8]; float b1v[2], wa2v[2];
  #pragma unroll
  for (int nt=0; nt<2; ++nt){
    int n = w*32 + nt*16 + lm;
    b1v[nt] = ba1[n]; wa2v[nt] = Wa2[n];
    #pragma unroll
    for (int kt=0; kt<8; ++kt)
      bwa[nt][kt] = cvt8(Wa1 + (size_t)n*256 + kt*32 + lk*8);
  }
  __syncthreads();

  #pragma unroll
  for (int mt=0; mt<4; ++mt){
    f32x4 a0 = {b1v[0],b1v[0],b1v[0],b1v[0]};
    f32x4 a1 = {b1v[1],b1v[1],b1v[1],b1v[1]};
    #pragma unroll
    for (int kt=0; kt<8; ++kt){
      int row = mt*16 + lm;
      s16x8 af = *(const s16x8*)((const char*)abuf + row*512 + (((kt*4+lk) ^ (row&15))<<4));
      a0 = MFMA(af, bwa[0][kt], a0);
      a1 = MFMA(af, bwa[1][kt], a1);
    }
    #pragma unroll
    for (int j=0; j<4; ++j){
      float pj = tanh_f(a0[j])*wa2v[0] + tanh_f(a1[j])*wa2v[1];
      #pragma unroll
      for (int m=1; m<16; m<<=1) pj += __shfl_xor(pj, m);
      if (lm == 0) scred[w][mt*16 + lk*4 + j] = pj;
    }
  }
  __syncthreads();
  if (tid < 64){
    float s = scred[0][tid]+scred[1][tid]+scred[2][tid]+scred[3][tid] + ba2[0];
    scores[(size_t)(bb+tid)*TT + t] = s;
  }
}

// ================= softmax over T + context =================
__global__ __launch_bounds__(256,2) void ctx_kernel(
    const uint16_t* __restrict__ h1, const float* __restrict__ scores,
    float* __restrict__ context, int BR)
{
  const int b = blockIdx.x, tid = threadIdx.x;
  __shared__ float at[TT];
  __shared__ float red[8];
  float sc = scores[(size_t)b*TT + tid];
  float m = sc;
  #pragma unroll
  for (int d=1; d<64; d<<=1) m = fmaxf(m, __shfl_xor(m, d));
  if ((tid&63)==0) red[tid>>6] = m;
  __syncthreads();
  m = fmaxf(fmaxf(red[0],red[1]), fmaxf(red[2],red[3]));
  float e = __expf(sc - m);
  float s = e;
  #pragma unroll
  for (int d=1; d<64; d<<=1) s += __shfl_xor(s, d);
  if ((tid&63)==0) red[4+(tid>>6)] = s;
  __syncthreads();
  s = red[4]+red[5]+red[6]+red[7];
  at[tid] = e / s;
  __syncthreads();

  float acc = 0.f;
  const uint16_t* hp = h1 + (size_t)b*256 + tid;
  #pragma unroll 4
  for (int t2=0; t2<TT; ++t2) acc += at[t2] * bf2f(hp[(size_t)t2*BR*256]);
  context[(size_t)b*256 + tid] = acc;
}

// ================= head =================
__global__ __launch_bounds__(128,2) void head_kernel(
    const float* __restrict__ ctx, const float* __restrict__ Wf1,
    const float* __restrict__ bf1, const float* __restrict__ g2,
    const float* __restrict__ b2, const float* __restrict__ Wf2,
    const float* __restrict__ bf2v, float* __restrict__ out, int b_off)
{
  const int b = blockIdx.x, tid = threadIdx.x;
  __shared__ float cx[256];
  __shared__ float zb[128];
  __shared__ float red[4];
  cx[tid]       = ctx[(size_t)b*256 + tid];
  cx[128+tid]   = ctx[(size_t)b*256 + 128 + tid];
  __syncthreads();
  float y = bf1[tid];
  const float* wr = Wf1 + (size_t)tid*256;
  #pragma unroll 8
  for (int k=0; k<256; ++k) y += cx[k]*wr[k];
  float s = y;
  #pragma unroll
  for (int d=1; d<64; d<<=1) s += __shfl_xor(s, d);
  if ((tid&63)==0) red[tid>>6] = s;
  __syncthreads();
  float mu = (red[0]+red[1])*(1.f/128.f);
  float dv = y - mu;
  float q = dv*dv;
  #pragma unroll
  for (int d=1; d<64; d<<=1) q += __shfl_xor(q, d);
  if ((tid&63)==0) red[2+(tid>>6)] = q;
  __syncthreads();
  float var = (red[2]+red[3])*(1.f/128.f);
  float z = dv*rsqrtf(var + 1e-5f)*g2[tid] + b2[tid];
  z = fmaxf(z, 0.f);
  zb[tid] = z;
  __syncthreads();
  if (tid < 5){
    float o = bf2v[tid];
    const float* wp = Wf2 + (size_t)tid*128;
    for (int k=0; k<128; ++k) o += zb[k]*wp[k];
    out[(size_t)(b_off + b)*5 + tid] = o;
  }
}

extern "C" void kernel_launch(void* const* d_in, const int* in_sizes, int n_in,
                              void* d_out, int out_size, void* d_ws, size_t ws_size,
                              hipStream_t stream)
{
  const float* x    = (const float*)d_in[0];
  const float* ln_g = (const float*)d_in[1];
  const float* ln_b = (const float*)d_in[2];
  const float* Wih0 = (const float*)d_in[3];
  const float* Whh0 = (const float*)d_in[4];
  const float* bih0 = (const float*)d_in[5];
  const float* bhh0 = (const float*)d_in[6];
  const float* Wih1 = (const float*)d_in[7];
  const float* Whh1 = (const float*)d_in[8];
  const float* bih1 = (const float*)d_in[9];
  const float* bhh1 = (const float*)d_in[10];
  const float* Wa1  = (const float*)d_in[11];
  const float* ba1  = (const float*)d_in[12];
  const float* Wa2  = (const float*)d_in[13];
  const float* ba2  = (const float*)d_in[14];
  const float* Wf1  = (const float*)d_in[15];
  const float* bf1  = (const float*)d_in[16];
  const float* ln2g = (const float*)d_in[17];
  const float* ln2b = (const float*)d_in[18];
  const float* Wf2  = (const float*)d_in[19];
  const float* bf2  = (const float*)d_in[20];
  float* out = (float*)d_out;

  char* wsb = (char*)d_ws;
  const size_t HBf = (size_t)TT*1024*256*2;   // 134,217,728
  const size_t HBh = (size_t)TT*512*256*2;    //  67,108,864

  if (ws_size >= 2*HBf){
    // ---------- FULL: whole batch, one lstm0 + one lstm1 dispatch ----------
    uint16_t* h0 = (uint16_t*)wsb;
    uint16_t* h1 = (uint16_t*)(wsb + HBf);
    float* scoresP = (float*)wsb;                       // alias dead h0
    float* ctxP    = (float*)(wsb + (size_t)1024*TT*4); // after scores, still in h0

    lstm_combo<<<256, 512, 0, stream>>>(256, 128, 1024, 0,
        x, ln_g, ln_b, Wih0, Whh0, bih0, bhh0, h0,
        128, 1024, h0, Wih1, Whh1, bih1, bhh1, h1);
    lstm_combo<<<256, 512, 0, stream>>>(0, 128, 1024, 0,
        x, ln_g, ln_b, Wih0, Whh0, bih0, bhh0, h0,
        128, 1024, h0, Wih1, Whh1, bih1, bhh1, h1);
    scores_kernel<<<TT*16, 256, 0, stream>>>(h1, Wa1, ba1, Wa2, ba2, scoresP, 16, 1024);
    ctx_kernel   <<<1024, 256, 0, stream>>>(h1, scoresP, ctxP, 1024);
    head_kernel  <<<1024, 128, 0, stream>>>(ctxP, Wf1, bf1, ln2g, ln2b, Wf2, bf2, out, 0);
  } else if (ws_size >= 3*HBh + 2*((size_t)512*TT*4)){
    // ---------- PIPE: BR=512, fat dispatch lstm1(A) || lstm0(B) ----------
    uint16_t* h0A = (uint16_t*)wsb;
    uint16_t* h0B = (uint16_t*)(wsb + HBh);
    uint16_t* h1A = (uint16_t*)(wsb + 2*HBh);
    uint16_t* h1B = h0A;                                 // alias dead h0A
    float* scoresP = (float*)(wsb + 3*HBh);
    float* ctxP    = (float*)(wsb + 3*HBh + (size_t)512*TT*4);

    lstm_combo<<<128, 512, 0, stream>>>(128, 64, 512, 0,
        x, ln_g, ln_b, Wih0, Whh0, bih0, bhh0, h0A,
        64, 512, h0A, Wih1, Whh1, bih1, bhh1, h1A);
    lstm_combo<<<256, 512, 0, stream>>>(128, 64, 512, 512,
        x, ln_g, ln_b, Wih0, Whh0, bih0, bhh0, h0B,
        64, 512, h0A, Wih1, Whh1, bih1, bhh1, h1A);
    lstm_combo<<<128, 512, 0, stream>>>(0, 64, 512, 0,
        x, ln_g, ln_b, Wih0, Whh0, bih0, bhh0, h0B,
        64, 512, h0B, Wih1, Whh1, bih1, bhh1, h1B);
    scores_kernel<<<TT*8, 256, 0, stream>>>(h1A, Wa1, ba1, Wa2, ba2, scoresP, 8, 512);
    ctx_kernel   <<<512, 256, 0, stream>>>(h1A, scoresP, ctxP, 512);
    head_kernel  <<<512, 128, 0, stream>>>(ctxP, Wf1, bf1, ln2g, ln2b, Wf2, bf2, out, 0);
    scores_kernel<<<TT*8, 256, 0, stream>>>(h1B, Wa1, ba1, Wa2, ba2, scoresP, 8, 512);
    ctx_kernel   <<<512, 256, 0, stream>>>(h1B, scoresP, ctxP, 512);
    head_kernel  <<<512, 128, 0, stream>>>(ctxP, Wf1, bf1, ln2g, ln2b, Wf2, bf2, out, 512);
  } else {
    // ---------- LOW: two serial rounds, two reused buffers ----------
    uint16_t* bufX = (uint16_t*)wsb;
    uint16_t* bufY = (uint16_t*)(wsb + HBh);
    float* scoresP = (float*)(wsb + 2*HBh);
    float* ctxP    = (float*)(wsb + 2*HBh + (size_t)512*TT*4);

    for (int r=0; r<2; ++r){
      int b_off = r*512;
      lstm_combo<<<128, 512, 0, stream>>>(128, 64, 512, b_off,
          x, ln_g, ln_b, Wih0, Whh0, bih0, bhh0, bufX,
          64, 512, bufX, Wih1, Whh1, bih1, bhh1, bufY);
      lstm_combo<<<128, 512, 0, stream>>>(0, 64, 512, b_off,
          x, ln_g, ln_b, Wih0, Whh0, bih0, bhh0, bufX,
          64, 512, bufX, Wih1, Whh1, bih1, bhh1, bufY);
      scores_kernel<<<TT*8, 256, 0, stream>>>(bufY, Wa1, ba1, Wa2, ba2, scoresP, 8, 512);
      ctx_kernel   <<<512, 256, 0, stream>>>(bufY, scoresP, ctxP, 512);
      head_kernel  <<<512, 128, 0, stream>>>(ctxP, Wf1, bf1, ln2g, ln2b, Wf2, bf2, out, b_off);
    }
  }
}